// Round 10
// baseline (365.544 us; speedup 1.0000x reference)
//
#include <hip/hip_runtime.h>
#include <hip/hip_bf16.h>
#include <cstdint>
#include <cstddef>

// MultiHeadAttention B=4, S=2048, D=1024, H=16, dk=64. fp32 in/out, bf16 MFMA internals.
// cvt fp32->bf16 (fused launch) -> fused QKV gemm (R8 single-buffer core, SWAPPED Q/K
// epilogues) -> flash attn (swapped 32x32x16, 64 q/wave two-group form: K/V fragments
// read once feed TWO MFMAs -> DS-pipe/FLOP halved; pf exchange shuffles halved by
// partner-operand pre-selection) -> out proj (SWAPPED float4 epilogue).

#define BATCH   4
#define SEQ     2048
#define D_MODEL 1024
#define NHEADS  16
#define DK      64

typedef __attribute__((ext_vector_type(8)))  __bf16 bf16x8_t;
typedef __attribute__((ext_vector_type(4)))  float  f32x4;
typedef __attribute__((ext_vector_type(16))) float  f32x16;

// HW packed fp32->bf16 (v_cvt_pk_bf16_f32 on gfx950)
__device__ inline unsigned int pack2(float lo, float hi) {
  __hip_bfloat162 h = __float22bfloat162_rn(make_float2(lo, hi));
  union { __hip_bfloat162 h; unsigned int u; } c; c.h = h; return c.u;
}
__device__ inline unsigned short f2bf(float f) { return (unsigned short)pack2(f, f); }

#if __has_builtin(__builtin_amdgcn_exp2f)
__device__ inline float fexp2(float x) { return __builtin_amdgcn_exp2f(x); }
#else
__device__ inline float fexp2(float x) { return __expf(x * 0.6931471805599453f); }
#endif

__device__ inline unsigned int exch32(unsigned int x) {  // partner lane^32 (verified prim)
  return (unsigned int)__shfl_xor((int)x, 32);
}

__device__ inline void cvt8(const float* __restrict__ s, unsigned short* __restrict__ d) {
  const float4 a = *(const float4*)s;
  const float4 b = *(const float4*)(s + 4);
  uint4 r;
  r.x = pack2(a.x, a.y); r.y = pack2(a.z, a.w);
  r.z = pack2(b.x, b.y); r.w = pack2(b.z, b.w);
  *(uint4*)d = r;
}

// async global->LDS, 16B/lane; LDS dest = wave-uniform base + lane*16B
typedef __attribute__((address_space(3))) unsigned int lds_u32_t;
typedef const __attribute__((address_space(1))) unsigned int glb_u32_t;
__device__ inline void gld16(const unsigned short* g, unsigned short* l) {
  __builtin_amdgcn_global_load_lds((glb_u32_t*)(uintptr_t)g,
                                   (lds_u32_t*)(unsigned int)(uintptr_t)l, 16, 0, 0);
}

// ---------------- fused fp32 -> bf16 conversion (3 activations + 4 weights, one launch) ----------------
__global__ __launch_bounds__(256) void cvt7_kernel(
    const float* __restrict__ a, const float* __restrict__ b, const float* __restrict__ c,
    const float* __restrict__ w0, const float* __restrict__ w1,
    const float* __restrict__ w2, const float* __restrict__ w3,
    unsigned short* __restrict__ oa, unsigned short* __restrict__ ob, unsigned short* __restrict__ oc,
    unsigned short* __restrict__ ow0, unsigned short* __restrict__ ow1,
    unsigned short* __restrict__ ow2, unsigned short* __restrict__ ow3)
{
  const int bx = blockIdx.x;
  const float* s;
  unsigned short* d;
  size_t local;
  if (bx < 12288) {                      // 3 tensors x 4096 blocks (E elems each)
    const int t = bx >> 12;
    local = (size_t)(bx & 4095);
    s = (t == 0) ? a : (t == 1) ? b : c;
    d = (t == 0) ? oa : (t == 1) ? ob : oc;
  } else {                               // 4 weights x 512 blocks (WE elems each)
    const int t = (bx - 12288) >> 9;
    local = (size_t)((bx - 12288) & 511);
    s = (t == 0) ? w0 : (t == 1) ? w1 : (t == 2) ? w2 : w3;
    d = (t == 0) ? ow0 : (t == 1) ? ow1 : (t == 2) ? ow2 : ow3;
  }
  const size_t i = (local * 256 + threadIdx.x) * 8;
  cvt8(s + i, d + i);
}

// ---------------- shared GEMM core (R8 form: single-buffer 2-barrier; dbuf regressed R9) ----------------
// SWAP=false: D[m=quad*4+reg, n=l15]  (C/D: col=lane&15, row=quad*4+reg [m89])
// SWAP=true : mfma(W,A) -> D[m=l15, n=quad*4+reg]
template <bool SWAP>
__device__ inline void gemm_core(const unsigned short* __restrict__ A,
                                 const unsigned short* __restrict__ W,
                                 unsigned short* a_lds, unsigned short* b_lds,
                                 int m0, int n0, f32x4 (&acc)[4][4])
{
  const int tid  = threadIdx.x;
  const int lane = tid & 63;
  const int wv   = tid >> 6;
  const int l15  = lane & 15;
  const int quad = lane >> 4;
  const int wm = (wv & 1) * 64;
  const int wn = (wv >> 1) * 64;

  const int srow = tid >> 2;
  const int sch  = (tid & 3) ^ (srow & 3);
  const unsigned short* Ap0 = A + (size_t)(m0 + srow) * D_MODEL + sch * 8;
  const unsigned short* Ap1 = Ap0 + (size_t)64 * D_MODEL;
  const unsigned short* Wp0 = W + (size_t)(n0 + srow) * D_MODEL + sch * 8;
  const unsigned short* Wp1 = Wp0 + (size_t)64 * D_MODEL;
  unsigned short* al0 = a_lds + wv * 512;
  unsigned short* al1 = a_lds + 2048 + wv * 512;
  unsigned short* bl0 = b_lds + wv * 512;
  unsigned short* bl1 = b_lds + 2048 + wv * 512;

  const int pq = (quad ^ (l15 & 3)) * 8;

  for (int k0 = 0; k0 < D_MODEL; k0 += 32) {
    __syncthreads();
    gld16(Ap0 + k0, al0);
    gld16(Ap1 + k0, al1);
    gld16(Wp0 + k0, bl0);
    gld16(Wp1 + k0, bl1);
    __syncthreads();

    bf16x8_t af[4], bfr[4];
#pragma unroll
    for (int i = 0; i < 4; ++i)
      af[i] = *(const bf16x8_t*)&a_lds[(wm + i * 16 + l15) * 32 + pq];
#pragma unroll
    for (int j = 0; j < 4; ++j)
      bfr[j] = *(const bf16x8_t*)&b_lds[(wn + j * 16 + l15) * 32 + pq];

#pragma unroll
    for (int i = 0; i < 4; ++i)
#pragma unroll
      for (int j = 0; j < 4; ++j) {
        if constexpr (SWAP)
          acc[i][j] = __builtin_amdgcn_mfma_f32_16x16x32_bf16(bfr[j], af[i], acc[i][j], 0, 0, 0);
        else
          acc[i][j] = __builtin_amdgcn_mfma_f32_16x16x32_bf16(af[i], bfr[j], acc[i][j], 0, 0, 0);
      }
  }
}

// ---------------- fused QKV projection ----------------
// grid (M/128, N/128, 3). z=0: Q (scaled log2e/8, SWAPPED -> uint2 scatter [B,H,S,dk]);
// z=1: K (SWAPPED -> uint2); z=2: V TRANSPOSED [B,H,dk,S] (non-swapped -> uint2).
__global__ __launch_bounds__(256) void qkv_kernel(
    const unsigned short* __restrict__ qb, const unsigned short* __restrict__ kb,
    const unsigned short* __restrict__ vb,
    const unsigned short* __restrict__ wq, const unsigned short* __restrict__ wk,
    const unsigned short* __restrict__ wvp,
    const float* __restrict__ bq, const float* __restrict__ bk, const float* __restrict__ bv,
    unsigned short* __restrict__ Qws, unsigned short* __restrict__ Kws,
    unsigned short* __restrict__ Vws)
{
  __shared__ unsigned short a_lds[128 * 32];
  __shared__ unsigned short b_lds[128 * 32];

  const int z = blockIdx.z;
  const unsigned short* A = (z == 0) ? qb : (z == 1) ? kb : vb;
  const unsigned short* W = (z == 0) ? wq : (z == 1) ? wk : wvp;
  const float* bias       = (z == 0) ? bq : (z == 1) ? bk : bv;
  unsigned short* C       = (z == 0) ? Qws : (z == 1) ? Kws : Vws;
  const int m0 = blockIdx.x * 128;
  const int n0 = blockIdx.y * 128;

  f32x4 acc[4][4];
#pragma unroll
  for (int i = 0; i < 4; ++i)
#pragma unroll
    for (int j = 0; j < 4; ++j)
      acc[i][j] = (f32x4){0.f, 0.f, 0.f, 0.f};

  const int tid  = threadIdx.x;
  const int lane = tid & 63;
  const int wv   = tid >> 6;
  const int l15  = lane & 15;
  const int quad = lane >> 4;
  const int wm = (wv & 1) * 64;
  const int wn = (wv >> 1) * 64;

  if (z == 2) {
    gemm_core<false>(A, W, a_lds, b_lds, m0, n0, acc);
    // D[m=quad*4+reg, n=l15]; V^T: off = ((bb*H+hh)*DK+dd)*SEQ + ss; 4 consecutive ss -> uint2
    for (int j = 0; j < 4; ++j) {
      const int n = n0 + wn + j * 16 + l15;
      const int hh = n >> 6, dd = n & 63;
      const float bvl = bias[n];
      for (int i = 0; i < 4; ++i) {
        const int mbase = m0 + wm + i * 16 + quad * 4;
        const int bb = mbase >> 11, ss = mbase & 2047;
        uint2 w2 = make_uint2(pack2(acc[i][j][0] + bvl, acc[i][j][1] + bvl),
                              pack2(acc[i][j][2] + bvl, acc[i][j][3] + bvl));
        *(uint2*)(C + (((size_t)bb * NHEADS + hh) * DK + dd) * SEQ + ss) = w2;
      }
    }
  } else {
    gemm_core<true>(A, W, a_lds, b_lds, m0, n0, acc);
    // SWAPPED: D[m=l15, n=quad*4+reg] -> 4 consecutive dd per lane (same head: quad*4+3<64)
    const float oscale = (z == 0) ? 0.18033688011112042f : 1.0f;  // log2(e)/8 for Q
    for (int j = 0; j < 4; ++j) {
      const int nb = n0 + wn + j * 16 + quad * 4;
      const int hh = nb >> 6, dd = nb & 63;
      const float4 b4 = *(const float4*)(bias + nb);
      for (int i = 0; i < 4; ++i) {
        const int m = m0 + wm + i * 16 + l15;
        const int bb = m >> 11, ss = m & 2047;
        uint2 w2 = make_uint2(pack2((acc[i][j][0] + b4.x) * oscale, (acc[i][j][1] + b4.y) * oscale),
                              pack2((acc[i][j][2] + b4.z) * oscale, (acc[i][j][3] + b4.w) * oscale));
        *(uint2*)(C + (((size_t)bb * NHEADS + hh) * SEQ + ss) * DK + dd) = w2;
      }
    }
  }
}

// ---------------- output projection (bf16 A, fp32 out, SWAPPED -> float4 epilogue) ----------------
__global__ __launch_bounds__(256) void outproj_kernel(
    const unsigned short* __restrict__ A, const unsigned short* __restrict__ W,
    const float* __restrict__ bias, float* __restrict__ C)
{
  __shared__ unsigned short a_lds[128 * 32];
  __shared__ unsigned short b_lds[128 * 32];
  const int m0 = blockIdx.x * 128;
  const int n0 = blockIdx.y * 128;

  f32x4 acc[4][4];
#pragma unroll
  for (int i = 0; i < 4; ++i)
#pragma unroll
    for (int j = 0; j < 4; ++j)
      acc[i][j] = (f32x4){0.f, 0.f, 0.f, 0.f};

  gemm_core<true>(A, W, a_lds, b_lds, m0, n0, acc);

  const int tid  = threadIdx.x;
  const int lane = tid & 63;
  const int wv   = tid >> 6;
  const int l15  = lane & 15;
  const int quad = lane >> 4;
  const int wm = (wv & 1) * 64;
  const int wn = (wv >> 1) * 64;
  // SWAPPED: D[m=l15, n=quad*4+reg] -> float4 store (nb 4-aligned -> 16B aligned)
  for (int j = 0; j < 4; ++j) {
    const int nb = n0 + wn + j * 16 + quad * 4;
    const float4 b4 = *(const float4*)(bias + nb);
    for (int i = 0; i < 4; ++i) {
      const int m = m0 + wm + i * 16 + l15;
      float4 o4 = make_float4(acc[i][j][0] + b4.x, acc[i][j][1] + b4.y,
                              acc[i][j][2] + b4.z, acc[i][j][3] + b4.w);
      *(float4*)(C + (size_t)m * D_MODEL + nb) = o4;
    }
  }
}

// ---------------- attn softmax helper (one 32-q group) ----------------
// Input s0/s1 = S^T scores (keys 0..31 / 32..63 rows per C/D map). Updates m,l,o (defer-max
// THR=8 base-2); emits PV B-fragments pf[0..3] via HALVED cross-half exchange: pre-select
// the word the PARTNER needs (t = hb ? w[0] : w[2]) so one exch32 serves both directions —
// algebraically identical to the R7-verified 4-shuffle form.
__device__ inline void softmax_group(const f32x16& s0, const f32x16& s1,
                                     float& mval, float& lval, f32x16 (&o)[2],
                                     bf16x8_t (&pf)[4], const int hb)
{
  float mx = s0[0];
#pragma unroll
  for (int i = 1; i < 16; ++i) mx = fmaxf(mx, s0[i]);
#pragma unroll
  for (int i = 0; i < 16; ++i) mx = fmaxf(mx, s1[i]);
  mx = fmaxf(mx, __shfl_xor(mx, 32));
  if (__any(mx > mval + 8.0f)) {
    const float mnew  = fmaxf(mval, mx);
    const float alpha = fexp2(mval - mnew);
    mval = mnew;
    lval *= alpha;
#pragma unroll
    for (int dh = 0; dh < 2; ++dh)
#pragma unroll
      for (int i = 0; i < 16; ++i) o[dh][i] *= alpha;
  }
  float rs = 0.f;
  unsigned int w0[8], w1[8];
#pragma unroll
  for (int m = 0; m < 8; ++m) {
    const float p0 = fexp2(s0[2 * m] - mval);
    const float p1 = fexp2(s0[2 * m + 1] - mval);
    rs += p0 + p1;
    w0[m] = pack2(p0, p1);
  }
#pragma unroll
  for (int m = 0; m < 8; ++m) {
    const float p0 = fexp2(s1[2 * m] - mval);
    const float p1 = fexp2(s1[2 * m + 1] - mval);
    rs += p0 + p1;
    w1[m] = pack2(p0, p1);
  }
  rs += __shfl_xor(rs, 32);
  lval += rs;

  union Cv { unsigned int w[4]; bf16x8_t v; };
#pragma unroll
  for (int f = 0; f < 4; ++f) {
    const unsigned int* w = (f < 2) ? (w0 + 4 * f) : (w1 + 4 * (f - 2));
    const unsigned int t0 = hb ? w[0] : w[2];
    const unsigned int t1 = hb ? w[1] : w[3];
    const unsigned int x0 = exch32(t0);
    const unsigned int x1 = exch32(t1);
    Cv c;
    c.w[0] = hb ? x0 : w[0];
    c.w[1] = hb ? x1 : w[1];
    c.w[2] = hb ? w[2] : x0;
    c.w[3] = hb ? w[3] : x1;
    pf[f] = c.v;
  }
}

// ---------------- Flash attention, swapped 32x32x16, 64 q/wave (two 32-q groups) ----------------
// 256 thr (4 waves), wave wv owns q-rows [q0+wv*64, +64) as groups A/B; grid (B*H, S/256).
// Per key-tile: each K/V fragment is read ONCE and feeds BOTH groups' MFMAs -> ds_read
// traffic per FLOP halved vs R7 (DS pipe = measured dominant consumer at 57%).
//   C/D: col = lane&31 = q, row = (reg&3)+8*(reg>>2)+4*(lane>>5)  [m74/m101]
// K/V^T DMA-staged double-buffered (R0-verified 2-slab staging), XOR swizzle
// chunk^(row&7)^(row>>3).
__global__ __launch_bounds__(256, 2) void attn_kernel(
    const unsigned short* __restrict__ Q,    // [B,H,S,dk]
    const unsigned short* __restrict__ K,    // [B,H,S,dk]
    const unsigned short* __restrict__ Vt,   // [B,H,dk,S]  (pre-transposed)
    unsigned short* __restrict__ Oattn)      // [B,S,D]
{
  __shared__ unsigned short k_sw[2 * 64 * 64];
  __shared__ unsigned short vt_sw[2 * 64 * 64];

  const int tid  = threadIdx.x;
  const int lane = tid & 63;
  const int wv   = tid >> 6;              // 0..3
  const int l31  = lane & 31;
  const int hb   = lane >> 5;             // half index
  const int bh   = blockIdx.x;            // bh-major: XCD = bh%8 -> K/V L2 locality
  const int q0   = blockIdx.y * 256;
  const size_t hoff = (size_t)bh * SEQ * DK;
  const unsigned short* Qh  = Q  + hoff;
  const unsigned short* Kh  = K  + hoff;
  const unsigned short* Vth = Vt + hoff;

  // Q fragments: group A q = q0 + wv*64 + l31, group B = +32; dk = kk*16 + hb*8 + j
  bf16x8_t qfA[4], qfB[4];
  {
    const unsigned short* qrA = Qh + (size_t)(q0 + wv * 64 + l31) * DK;
    const unsigned short* qrB = qrA + (size_t)32 * DK;
#pragma unroll
    for (int kk = 0; kk < 4; ++kk) {
      qfA[kk] = *(const bf16x8_t*)(qrA + kk * 16 + hb * 8);
      qfB[kk] = *(const bf16x8_t*)(qrB + kk * 16 + hb * 8);
    }
  }

  f32x16 oA[2], oB[2];
#pragma unroll
  for (int dh = 0; dh < 2; ++dh)
#pragma unroll
    for (int i = 0; i < 16; ++i) { oA[dh][i] = 0.f; oB[dh][i] = 0.f; }
  float mA = -1e30f, lA = 0.f;
  float mB = -1e30f, lB = 0.f;

  // DMA staging: wave wv covers tile rows [wv*16, wv*16+16) of K and V^T (2 gld16 each).
  const int sr  = lane >> 3;              // 0..7
  const int pc  = lane & 7;               // phys chunk
  const int r0  = wv * 16 + sr;           // r0>>3 = 2wv
  const int r1  = r0 + 8;                 // r1>>3 = 2wv+1
  const int sem0 = pc ^ sr ^ (2 * wv);
  const int sem1 = pc ^ sr ^ (2 * wv + 1);
  const unsigned short* KsA = Kh  + (size_t)r0 * DK  + sem0 * 8;   // + key0*DK per iter
  const unsigned short* KsB = Kh  + (size_t)r1 * DK  + sem1 * 8;
  const unsigned short* VsA = Vth + (size_t)r0 * SEQ + sem0 * 8;   // + key0 per iter
  const unsigned short* VsB = Vth + (size_t)r1 * SEQ + sem1 * 8;
  unsigned short* kd = k_sw  + wv * 1024;
  unsigned short* vd = vt_sw + wv * 1024;

#define STAGE(buf, key0) do {                                        \
    gld16(KsA + (size_t)(key0) * DK, kd + (buf) * 4096);             \
    gld16(KsB + (size_t)(key0) * DK, kd + (buf) * 4096 + 512);       \
    gld16(VsA + (key0),              vd + (buf) * 4096);             \
    gld16(VsB + (key0),              vd + (buf) * 4096 + 512);       \
  } while (0)

  // prologue: stage tile 0 into buffer 0
  STAGE(0, 0);
  __syncthreads();                         // drains vmcnt(0): tile 0 resident

  const int swr0 = (l31 & 7) ^ (l31 >> 3);         // swizzle for rows l31      (slice 0)
  const int swr1 = (l31 & 7) ^ ((l31 >> 3) ^ 4);   // swizzle for rows 32+l31   (slice 1)

  int cur = 0;
  for (int kb = 0; kb < SEQ / 64; ++kb) {
    if (kb + 1 < SEQ / 64) STAGE(cur ^ 1, (kb + 1) * 64);

    const unsigned short* kcur = k_sw  + cur * 4096;
    const unsigned short* vcur = vt_sw + cur * 4096;

    // S^T = K·Q^T for BOTH groups; each kf read once, used twice
    f32x16 sA0, sA1, sB0, sB1;
#pragma unroll
    for (int i = 0; i < 16; ++i) { sA0[i] = 0.f; sA1[i] = 0.f; sB0[i] = 0.f; sB1[i] = 0.f; }
    __builtin_amdgcn_s_setprio(1);
    {
      const unsigned short* krow = kcur + l31 * 64;
#pragma unroll
      for (int kk = 0; kk < 4; ++kk) {
        bf16x8_t kf = *(const bf16x8_t*)&krow[((2 * kk + hb) ^ swr0) << 3];
        sA0 = __builtin_amdgcn_mfma_f32_32x32x16_bf16(kf, qfA[kk], sA0, 0, 0, 0);
        sB0 = __builtin_amdgcn_mfma_f32_32x32x16_bf16(kf, qfB[kk], sB0, 0, 0, 0);
      }
    }
    {
      const unsigned short* krow = kcur + (32 + l31) * 64;
#pragma unroll
      for (int kk = 0; kk < 4; ++kk) {
        bf16x8_t kf = *(const bf16x8_t*)&krow[((2 * kk + hb) ^ swr1) << 3];
        sA1 = __builtin_amdgcn_mfma_f32_32x32x16_bf16(kf, qfA[kk], sA1, 0, 0, 0);
        sB1 = __builtin_amdgcn_mfma_f32_32x32x16_bf16(kf, qfB[kk], sB1, 0, 0, 0);
      }
    }
    __builtin_amdgcn_s_setprio(0);

    bf16x8_t pfA[4], pfB[4];
    softmax_group(sA0, sA1, mA, lA, oA, pfA, hb);
    softmax_group(sB0, sB1, mB, lB, oB, pfB, hb);

    // O^T += V^T · P^T; each vf read once, used twice
    __builtin_amdgcn_s_setprio(1);
    {
      const unsigned short* vrow = vcur + l31 * 64;
#pragma unroll
      for (int t = 0; t < 4; ++t) {
        bf16x8_t vf = *(const bf16x8_t*)&vrow[((2 * t + hb) ^ swr0) << 3];
        oA[0] = __builtin_amdgcn_mfma_f32_32x32x16_bf16(vf, pfA[t], oA[0], 0, 0, 0);
        oB[0] = __builtin_amdgcn_mfma_f32_32x32x16_bf16(vf, pfB[t], oB[0], 0, 0, 0);
      }
    }
    {
      const unsigned short* vrow = vcur + (32 + l31) * 64;
#pragma unroll
      for (int t = 0; t < 4; ++t) {
        bf16x8_t vf = *(const bf16x8_t*)&vrow[((2 * t + hb) ^ swr1) << 3];
        oA[1] = __builtin_amdgcn_mfma_f32_32x32x16_bf16(vf, pfA[t], oA[1], 0, 0, 0);
        oB[1] = __builtin_amdgcn_mfma_f32_32x32x16_bf16(vf, pfB[t], oB[1], 0, 0, 0);
      }
    }
    __builtin_amdgcn_s_setprio(0);

    // single barrier per iter: drains this iter's prefetch (vmcnt) AND all waves' LDS reads
    __syncthreads();
    cur ^= 1;
  }
#undef STAGE

  // epilogue: group A q = q0+wv*64+l31, group B +32; d = 32*dh + 8*a + 4*hb + c (reg=4a+c)
  const int bb = bh >> 4, hh = bh & 15;
  {
    const float inv = 1.0f / lA;
    unsigned short* orow = Oattn + (size_t)(bb * SEQ + q0 + wv * 64 + l31) * D_MODEL
                         + hh * DK + hb * 4;
#pragma unroll
    for (int dh = 0; dh < 2; ++dh)
#pragma unroll
      for (int a = 0; a < 4; ++a) {
        const float v0 = oA[dh][4 * a]     * inv;
        const float v1 = oA[dh][4 * a + 1] * inv;
        const float v2 = oA[dh][4 * a + 2] * inv;
        const float v3 = oA[dh][4 * a + 3] * inv;
        *(uint2*)(orow + dh * 32 + a * 8) = make_uint2(pack2(v0, v1), pack2(v2, v3));
      }
  }
  {
    const float inv = 1.0f / lB;
    unsigned short* orow = Oattn + (size_t)(bb * SEQ + q0 + wv * 64 + 32 + l31) * D_MODEL
                         + hh * DK + hb * 4;
#pragma unroll
    for (int dh = 0; dh < 2; ++dh)
#pragma unroll
      for (int a = 0; a < 4; ++a) {
        const float v0 = oB[dh][4 * a]     * inv;
        const float v1 = oB[dh][4 * a + 1] * inv;
        const float v2 = oB[dh][4 * a + 2] * inv;
        const float v3 = oB[dh][4 * a + 3] * inv;
        *(uint2*)(orow + dh * 32 + a * 8) = make_uint2(pack2(v0, v1), pack2(v2, v3));
      }
  }
}

extern "C" void kernel_launch(void* const* d_in, const int* in_sizes, int n_in,
                              void* d_out, int out_size, void* d_ws, size_t ws_size,
                              hipStream_t stream) {
  const float* query = (const float*)d_in[0];
  const float* key   = (const float*)d_in[1];
  const float* value = (const float*)d_in[2];
  const float* Wq    = (const float*)d_in[3];
  const float* bq    = (const float*)d_in[4];
  const float* Wk    = (const float*)d_in[5];
  const float* bk    = (const float*)d_in[6];
  const float* Wv    = (const float*)d_in[7];
  const float* bv    = (const float*)d_in[8];
  const float* Wo    = (const float*)d_in[9];
  const float* bo    = (const float*)d_in[10];

  const size_t E  = (size_t)BATCH * SEQ * D_MODEL;   // 8,388,608
  const size_t WE = (size_t)D_MODEL * D_MODEL;       // 1,048,576
  unsigned short* ws  = (unsigned short*)d_ws;
  unsigned short* Qws = ws;                          // [B,H,S,dk], pre-scaled log2e/8
  unsigned short* Kws = ws + E;
  unsigned short* Vws = ws + 2 * E;                  // [B,H,dk,S] transposed
  unsigned short* qb  = ws + 3 * E;
  unsigned short* kb  = ws + 4 * E;
  unsigned short* vb  = ws + 5 * E;
  unsigned short* wqb = ws + 6 * E;
  unsigned short* wkb = wqb + WE;
  unsigned short* wvb = wqb + 2 * WE;
  unsigned short* wob = wqb + 3 * WE;
  unsigned short* Aws = qb;                          // alias: qb dead after QKV GEMM

  cvt7_kernel<<<dim3(12288 + 2048), 256, 0, stream>>>(
      query, key, value, Wq, Wk, Wv, Wo, qb, kb, vb, wqb, wkb, wvb, wob);

  qkv_kernel<<<dim3(BATCH * SEQ / 128, D_MODEL / 128, 3), 256, 0, stream>>>(
      qb, kb, vb, wqb, wkb, wvb, bq, bk, bv, Qws, Kws, Vws);
  attn_kernel<<<dim3(BATCH * NHEADS, SEQ / 256), 256, 0, stream>>>(Qws, Kws, Vws, Aws);
  outproj_kernel<<<dim3(BATCH * SEQ / 128, D_MODEL / 128), 256, 0, stream>>>(
      Aws, wob, bo, (float*)d_out);
}

// Round 11
// 354.879 us; speedup vs baseline: 1.0300x; 1.0300x over previous
//
#include <hip/hip_runtime.h>
#include <hip/hip_bf16.h>
#include <cstdint>
#include <cstddef>

// MultiHeadAttention B=4, S=2048, D=1024, H=16, dk=64. fp32 in/out, bf16 MFMA internals.
// cvt fp32->bf16 (fused launch) -> fused QKV gemm (R8 2-barrier core, SWAPPED Q/K
// epilogues, XCD-aware block swizzle for A-panel L2 locality) -> flash attn (R7 512-thr
// structure, frozen at 113.5us) -> out proj (SWAPPED float4 epilogue + XCD swizzle).

#define BATCH   4
#define SEQ     2048
#define D_MODEL 1024
#define NHEADS  16
#define DK      64

typedef __attribute__((ext_vector_type(8)))  __bf16 bf16x8_t;
typedef __attribute__((ext_vector_type(4)))  float  f32x4;
typedef __attribute__((ext_vector_type(16))) float  f32x16;

// HW packed fp32->bf16 (v_cvt_pk_bf16_f32 on gfx950)
__device__ inline unsigned int pack2(float lo, float hi) {
  __hip_bfloat162 h = __float22bfloat162_rn(make_float2(lo, hi));
  union { __hip_bfloat162 h; unsigned int u; } c; c.h = h; return c.u;
}
__device__ inline unsigned short f2bf(float f) { return (unsigned short)pack2(f, f); }

#if __has_builtin(__builtin_amdgcn_exp2f)
__device__ inline float fexp2(float x) { return __builtin_amdgcn_exp2f(x); }
#else
__device__ inline float fexp2(float x) { return __expf(x * 0.6931471805599453f); }
#endif

__device__ inline unsigned int exch32(unsigned int x) {  // partner lane^32 (verified prim)
  return (unsigned int)__shfl_xor((int)x, 32);
}

__device__ inline void cvt8(const float* __restrict__ s, unsigned short* __restrict__ d) {
  const float4 a = *(const float4*)s;
  const float4 b = *(const float4*)(s + 4);
  uint4 r;
  r.x = pack2(a.x, a.y); r.y = pack2(a.z, a.w);
  r.z = pack2(b.x, b.y); r.w = pack2(b.z, b.w);
  *(uint4*)d = r;
}

// async global->LDS, 16B/lane; LDS dest = wave-uniform base + lane*16B
typedef __attribute__((address_space(3))) unsigned int lds_u32_t;
typedef const __attribute__((address_space(1))) unsigned int glb_u32_t;
__device__ inline void gld16(const unsigned short* g, unsigned short* l) {
  __builtin_amdgcn_global_load_lds((glb_u32_t*)(uintptr_t)g,
                                   (lds_u32_t*)(unsigned int)(uintptr_t)l, 16, 0, 0);
}

// ---------------- fused fp32 -> bf16 conversion (3 activations + 4 weights, one launch) ----------------
__global__ __launch_bounds__(256) void cvt7_kernel(
    const float* __restrict__ a, const float* __restrict__ b, const float* __restrict__ c,
    const float* __restrict__ w0, const float* __restrict__ w1,
    const float* __restrict__ w2, const float* __restrict__ w3,
    unsigned short* __restrict__ oa, unsigned short* __restrict__ ob, unsigned short* __restrict__ oc,
    unsigned short* __restrict__ ow0, unsigned short* __restrict__ ow1,
    unsigned short* __restrict__ ow2, unsigned short* __restrict__ ow3)
{
  const int bx = blockIdx.x;
  const float* s;
  unsigned short* d;
  size_t local;
  if (bx < 12288) {                      // 3 tensors x 4096 blocks (E elems each)
    const int t = bx >> 12;
    local = (size_t)(bx & 4095);
    s = (t == 0) ? a : (t == 1) ? b : c;
    d = (t == 0) ? oa : (t == 1) ? ob : oc;
  } else {                               // 4 weights x 512 blocks (WE elems each)
    const int t = (bx - 12288) >> 9;
    local = (size_t)((bx - 12288) & 511);
    s = (t == 0) ? w0 : (t == 1) ? w1 : (t == 2) ? w2 : w3;
    d = (t == 0) ? ow0 : (t == 1) ? ow1 : (t == 2) ? ow2 : ow3;
  }
  const size_t i = (local * 256 + threadIdx.x) * 8;
  cvt8(s + i, d + i);
}

// XCD-aware swizzle (T1, m157): linear dispatch id -> (m_idx, n_idx) such that all 8
// n-blocks sharing an A-panel land on ONE XCD (XCD = lid%8 on 8-XCD MI355X).
// lid in [0,512): swz = (lid%8)*64 + lid/8; m_idx = swz>>3 (0..63), n_idx = swz&7.
// XCD c covers m panels [8c,8c+8) x all n -> each A-panel fetched by exactly one XCD;
// per-XCD L2 working set = 8 A-panels (2MB) + W (2MB) = 4MB. Bijective (512%8==0).
__device__ inline void xcd_mn(int lid, int& m_idx, int& n_idx) {
  const int swz = (lid & 7) * 64 + (lid >> 3);
  m_idx = swz >> 3;
  n_idx = swz & 7;
}

// ---------------- shared GEMM core (R8 form: single-buffer 2-barrier) ----------------
// SWAP=false: D[m=quad*4+reg, n=l15]  (C/D: col=lane&15, row=quad*4+reg [m89])
// SWAP=true : mfma(W,A) -> D[m=l15, n=quad*4+reg]
template <bool SWAP>
__device__ inline void gemm_core(const unsigned short* __restrict__ A,
                                 const unsigned short* __restrict__ W,
                                 unsigned short* a_lds, unsigned short* b_lds,
                                 int m0, int n0, f32x4 (&acc)[4][4])
{
  const int tid  = threadIdx.x;
  const int lane = tid & 63;
  const int wv   = tid >> 6;
  const int l15  = lane & 15;
  const int quad = lane >> 4;
  const int wm = (wv & 1) * 64;
  const int wn = (wv >> 1) * 64;

  const int srow = tid >> 2;
  const int sch  = (tid & 3) ^ (srow & 3);
  const unsigned short* Ap0 = A + (size_t)(m0 + srow) * D_MODEL + sch * 8;
  const unsigned short* Ap1 = Ap0 + (size_t)64 * D_MODEL;
  const unsigned short* Wp0 = W + (size_t)(n0 + srow) * D_MODEL + sch * 8;
  const unsigned short* Wp1 = Wp0 + (size_t)64 * D_MODEL;
  unsigned short* al0 = a_lds + wv * 512;
  unsigned short* al1 = a_lds + 2048 + wv * 512;
  unsigned short* bl0 = b_lds + wv * 512;
  unsigned short* bl1 = b_lds + 2048 + wv * 512;

  const int pq = (quad ^ (l15 & 3)) * 8;

  for (int k0 = 0; k0 < D_MODEL; k0 += 32) {
    __syncthreads();
    gld16(Ap0 + k0, al0);
    gld16(Ap1 + k0, al1);
    gld16(Wp0 + k0, bl0);
    gld16(Wp1 + k0, bl1);
    __syncthreads();

    bf16x8_t af[4], bfr[4];
#pragma unroll
    for (int i = 0; i < 4; ++i)
      af[i] = *(const bf16x8_t*)&a_lds[(wm + i * 16 + l15) * 32 + pq];
#pragma unroll
    for (int j = 0; j < 4; ++j)
      bfr[j] = *(const bf16x8_t*)&b_lds[(wn + j * 16 + l15) * 32 + pq];

#pragma unroll
    for (int i = 0; i < 4; ++i)
#pragma unroll
      for (int j = 0; j < 4; ++j) {
        if constexpr (SWAP)
          acc[i][j] = __builtin_amdgcn_mfma_f32_16x16x32_bf16(bfr[j], af[i], acc[i][j], 0, 0, 0);
        else
          acc[i][j] = __builtin_amdgcn_mfma_f32_16x16x32_bf16(af[i], bfr[j], acc[i][j], 0, 0, 0);
      }
  }
}

// ---------------- fused QKV projection ----------------
// grid (512, 1, 3) linear; XCD-swizzled (m_idx, n_idx). z=0: Q (scaled log2e/8, SWAPPED ->
// uint2 scatter [B,H,S,dk]); z=1: K (SWAPPED -> uint2); z=2: V TRANSPOSED [B,H,dk,S].
__global__ __launch_bounds__(256) void qkv_kernel(
    const unsigned short* __restrict__ qb, const unsigned short* __restrict__ kb,
    const unsigned short* __restrict__ vb,
    const unsigned short* __restrict__ wq, const unsigned short* __restrict__ wk,
    const unsigned short* __restrict__ wvp,
    const float* __restrict__ bq, const float* __restrict__ bk, const float* __restrict__ bv,
    unsigned short* __restrict__ Qws, unsigned short* __restrict__ Kws,
    unsigned short* __restrict__ Vws)
{
  __shared__ unsigned short a_lds[128 * 32];
  __shared__ unsigned short b_lds[128 * 32];

  const int z = blockIdx.z;
  const unsigned short* A = (z == 0) ? qb : (z == 1) ? kb : vb;
  const unsigned short* W = (z == 0) ? wq : (z == 1) ? wk : wvp;
  const float* bias       = (z == 0) ? bq : (z == 1) ? bk : bv;
  unsigned short* C       = (z == 0) ? Qws : (z == 1) ? Kws : Vws;
  int m_idx, n_idx;
  xcd_mn(blockIdx.x, m_idx, n_idx);
  const int m0 = m_idx * 128;
  const int n0 = n_idx * 128;

  f32x4 acc[4][4];
#pragma unroll
  for (int i = 0; i < 4; ++i)
#pragma unroll
    for (int j = 0; j < 4; ++j)
      acc[i][j] = (f32x4){0.f, 0.f, 0.f, 0.f};

  const int tid  = threadIdx.x;
  const int lane = tid & 63;
  const int wv   = tid >> 6;
  const int l15  = lane & 15;
  const int quad = lane >> 4;
  const int wm = (wv & 1) * 64;
  const int wn = (wv >> 1) * 64;

  if (z == 2) {
    gemm_core<false>(A, W, a_lds, b_lds, m0, n0, acc);
    // D[m=quad*4+reg, n=l15]; V^T: off = ((bb*H+hh)*DK+dd)*SEQ + ss; 4 consecutive ss -> uint2
    for (int j = 0; j < 4; ++j) {
      const int n = n0 + wn + j * 16 + l15;
      const int hh = n >> 6, dd = n & 63;
      const float bvl = bias[n];
      for (int i = 0; i < 4; ++i) {
        const int mbase = m0 + wm + i * 16 + quad * 4;
        const int bb = mbase >> 11, ss = mbase & 2047;
        uint2 w2 = make_uint2(pack2(acc[i][j][0] + bvl, acc[i][j][1] + bvl),
                              pack2(acc[i][j][2] + bvl, acc[i][j][3] + bvl));
        *(uint2*)(C + (((size_t)bb * NHEADS + hh) * DK + dd) * SEQ + ss) = w2;
      }
    }
  } else {
    gemm_core<true>(A, W, a_lds, b_lds, m0, n0, acc);
    // SWAPPED: D[m=l15, n=quad*4+reg] -> 4 consecutive dd per lane (same head: quad*4+3<64)
    const float oscale = (z == 0) ? 0.18033688011112042f : 1.0f;  // log2(e)/8 for Q
    for (int j = 0; j < 4; ++j) {
      const int nb = n0 + wn + j * 16 + quad * 4;
      const int hh = nb >> 6, dd = nb & 63;
      const float4 b4 = *(const float4*)(bias + nb);
      for (int i = 0; i < 4; ++i) {
        const int m = m0 + wm + i * 16 + l15;
        const int bb = m >> 11, ss = m & 2047;
        uint2 w2 = make_uint2(pack2((acc[i][j][0] + b4.x) * oscale, (acc[i][j][1] + b4.y) * oscale),
                              pack2((acc[i][j][2] + b4.z) * oscale, (acc[i][j][3] + b4.w) * oscale));
        *(uint2*)(C + (((size_t)bb * NHEADS + hh) * SEQ + ss) * DK + dd) = w2;
      }
    }
  }
}

// ---------------- output projection (bf16 A, fp32 out, SWAPPED -> float4, XCD swizzle) ----------------
__global__ __launch_bounds__(256) void outproj_kernel(
    const unsigned short* __restrict__ A, const unsigned short* __restrict__ W,
    const float* __restrict__ bias, float* __restrict__ C)
{
  __shared__ unsigned short a_lds[128 * 32];
  __shared__ unsigned short b_lds[128 * 32];
  int m_idx, n_idx;
  xcd_mn(blockIdx.x, m_idx, n_idx);
  const int m0 = m_idx * 128;
  const int n0 = n_idx * 128;

  f32x4 acc[4][4];
#pragma unroll
  for (int i = 0; i < 4; ++i)
#pragma unroll
    for (int j = 0; j < 4; ++j)
      acc[i][j] = (f32x4){0.f, 0.f, 0.f, 0.f};

  gemm_core<true>(A, W, a_lds, b_lds, m0, n0, acc);

  const int tid  = threadIdx.x;
  const int lane = tid & 63;
  const int wv   = tid >> 6;
  const int l15  = lane & 15;
  const int quad = lane >> 4;
  const int wm = (wv & 1) * 64;
  const int wn = (wv >> 1) * 64;
  // SWAPPED: D[m=l15, n=quad*4+reg] -> float4 store (nb 4-aligned -> 16B aligned)
  for (int j = 0; j < 4; ++j) {
    const int nb = n0 + wn + j * 16 + quad * 4;
    const float4 b4 = *(const float4*)(bias + nb);
    for (int i = 0; i < 4; ++i) {
      const int m = m0 + wm + i * 16 + l15;
      float4 o4 = make_float4(acc[i][j][0] + b4.x, acc[i][j][1] + b4.y,
                              acc[i][j][2] + b4.z, acc[i][j][3] + b4.w);
      *(float4*)(C + (size_t)m * D_MODEL + nb) = o4;
    }
  }
}

// ---------------- Flash attention, swapped 32x32x16 form (R7, frozen at 113.5us) ----------------
// 512 thr (8 waves), wave wv owns 32 q-rows (q0 + wv*32 + l31); grid (B*H, S/256).
// S^T[64k x 32q] = K·Q^T via 2 key-slices x 4 dk-slices of mfma_32x32x16.
//   C/D: col = lane&31 = q, row = (reg&3)+8*(reg>>2)+4*(lane>>5)  [m74/m101]
// Cross-half combines + P^T B-fragment build via __shfl_xor(.,32).
// K/V^T DMA-staged double-buffered, source-side XOR swizzle chunk^(row&7)^(row>>3).
__global__ __launch_bounds__(512, 4) void attn_kernel(
    const unsigned short* __restrict__ Q,    // [B,H,S,dk]
    const unsigned short* __restrict__ K,    // [B,H,S,dk]
    const unsigned short* __restrict__ Vt,   // [B,H,dk,S]  (pre-transposed)
    unsigned short* __restrict__ Oattn)      // [B,S,D]
{
  __shared__ unsigned short k_sw[2 * 64 * 64];
  __shared__ unsigned short vt_sw[2 * 64 * 64];

  const int tid  = threadIdx.x;
  const int lane = tid & 63;
  const int wv   = tid >> 6;              // 0..7
  const int l31  = lane & 31;
  const int hb   = lane >> 5;             // half index
  const int bh   = blockIdx.x;            // bh-major: XCD = bh%8 -> K/V L2 locality
  const int q0   = blockIdx.y * 256;
  const size_t hoff = (size_t)bh * SEQ * DK;
  const unsigned short* Qh  = Q  + hoff;
  const unsigned short* Kh  = K  + hoff;
  const unsigned short* Vth = Vt + hoff;

  // Q fragments: q = q0 + wv*32 + l31, dk = kk*16 + hb*8 + j
  bf16x8_t qf[4];
  {
    const unsigned short* qr = Qh + (size_t)(q0 + wv * 32 + l31) * DK;
#pragma unroll
    for (int kk = 0; kk < 4; ++kk)
      qf[kk] = *(const bf16x8_t*)(qr + kk * 16 + hb * 8);
  }

  f32x16 oAcc[2];
#pragma unroll
  for (int dh = 0; dh < 2; ++dh)
#pragma unroll
    for (int i = 0; i < 16; ++i) oAcc[dh][i] = 0.f;
  float mval = -1e30f, lval = 0.f;

  // DMA staging: wave wv covers tile rows [wv*8, wv*8+8) of K and of V^T (1 gld16 each).
  const int sr  = lane >> 3;              // 0..7 (row within the wave's 8-row slab)
  const int pc  = lane & 7;               // phys chunk
  const int row = wv * 8 + sr;
  const int sem = pc ^ sr ^ wv;           // (row&7)=sr, (row>>3)=wv
  const unsigned short* KsA = Kh  + (size_t)row * DK  + sem * 8;   // + key0*DK per iter
  const unsigned short* VsA = Vth + (size_t)row * SEQ + sem * 8;   // + key0 per iter
  unsigned short* kd = k_sw  + wv * 512;
  unsigned short* vd = vt_sw + wv * 512;

#define STAGE(buf, key0) do {                                        \
    gld16(KsA + (size_t)(key0) * DK, kd + (buf) * 4096);             \
    gld16(VsA + (key0),              vd + (buf) * 4096);             \
  } while (0)

  // prologue: stage tile 0 into buffer 0
  STAGE(0, 0);
  __syncthreads();                         // drains vmcnt(0): tile 0 resident

  const int swr0 = (l31 & 7) ^ (l31 >> 3);         // swizzle for rows l31      (slice 0)
  const int swr1 = (l31 & 7) ^ ((l31 >> 3) ^ 4);   // swizzle for rows 32+l31   (slice 1)

  int cur = 0;
  for (int kb = 0; kb < SEQ / 64; ++kb) {
    // issue next tile's loads FIRST so they overlap this tile's compute
    if (kb + 1 < SEQ / 64) STAGE(cur ^ 1, (kb + 1) * 64);

    const unsigned short* kcur = k_sw  + cur * 4096;
    const unsigned short* vcur = vt_sw + cur * 4096;

    // S^T = K·Q^T : s0 = keys 0..31 rows, s1 = keys 32..63 rows (per C/D row map)
    f32x16 s0, s1;
#pragma unroll
    for (int i = 0; i < 16; ++i) { s0[i] = 0.f; s1[i] = 0.f; }
    __builtin_amdgcn_s_setprio(1);
    {
      const unsigned short* krow = kcur + l31 * 64;
#pragma unroll
      for (int kk = 0; kk < 4; ++kk) {
        bf16x8_t kf = *(const bf16x8_t*)&krow[((2 * kk + hb) ^ swr0) << 3];
        s0 = __builtin_amdgcn_mfma_f32_32x32x16_bf16(kf, qf[kk], s0, 0, 0, 0);
      }
    }
    {
      const unsigned short* krow = kcur + (32 + l31) * 64;
#pragma unroll
      for (int kk = 0; kk < 4; ++kk) {
        bf16x8_t kf = *(const bf16x8_t*)&krow[((2 * kk + hb) ^ swr1) << 3];
        s1 = __builtin_amdgcn_mfma_f32_32x32x16_bf16(kf, qf[kk], s1, 0, 0, 0);
      }
    }
    __builtin_amdgcn_s_setprio(0);

    // row-max over own 32 scores + cross-half combine (verified shfl_xor)
    float mx = s0[0];
#pragma unroll
    for (int i = 1; i < 16; ++i) mx = fmaxf(mx, s0[i]);
#pragma unroll
    for (int i = 0; i < 16; ++i) mx = fmaxf(mx, s1[i]);
    mx = fmaxf(mx, __shfl_xor(mx, 32));
    // defer-max (T13, THR=8 in base-2 units => P <= 2^8)
    if (__any(mx > mval + 8.0f)) {
      const float mnew  = fmaxf(mval, mx);
      const float alpha = fexp2(mval - mnew);
      mval = mnew;
      lval *= alpha;
#pragma unroll
      for (int dh = 0; dh < 2; ++dh)
#pragma unroll
        for (int i = 0; i < 16; ++i) oAcc[dh][i] *= alpha;
    }
    // p = exp2(s - m), pack to bf16 words; w[m] = pack(regs 2m, 2m+1)
    float rs = 0.f;
    unsigned int w0[8], w1[8];
#pragma unroll
    for (int m = 0; m < 8; ++m) {
      const float p0 = fexp2(s0[2 * m] - mval);
      const float p1 = fexp2(s0[2 * m + 1] - mval);
      rs += p0 + p1;
      w0[m] = pack2(p0, p1);
    }
#pragma unroll
    for (int m = 0; m < 8; ++m) {
      const float p0 = fexp2(s1[2 * m] - mval);
      const float p1 = fexp2(s1[2 * m + 1] - mval);
      rs += p0 + p1;
      w1[m] = pack2(p0, p1);
    }
    rs += __shfl_xor(rs, 32);
    lval += rs;

    // P^T -> PV B-fragments via verified cross-half exchange
    union Cv { unsigned int w[4]; bf16x8_t v; };
    bf16x8_t pf[4];
    {
      const unsigned int e0 = exch32(w0[0]), e1 = exch32(w0[1]);
      const unsigned int e2 = exch32(w0[2]), e3 = exch32(w0[3]);
      Cv c;
      c.w[0] = hb ? e2 : w0[0]; c.w[1] = hb ? e3 : w0[1];
      c.w[2] = hb ? w0[2] : e0; c.w[3] = hb ? w0[3] : e1;
      pf[0] = c.v;
    }
    {
      const unsigned int e0 = exch32(w0[4]), e1 = exch32(w0[5]);
      const unsigned int e2 = exch32(w0[6]), e3 = exch32(w0[7]);
      Cv c;
      c.w[0] = hb ? e2 : w0[4]; c.w[1] = hb ? e3 : w0[5];
      c.w[2] = hb ? w0[6] : e0; c.w[3] = hb ? w0[7] : e1;
      pf[1] = c.v;
    }
    {
      const unsigned int e0 = exch32(w1[0]), e1 = exch32(w1[1]);
      const unsigned int e2 = exch32(w1[2]), e3 = exch32(w1[3]);
      Cv c;
      c.w[0] = hb ? e2 : w1[0]; c.w[1] = hb ? e3 : w1[1];
      c.w[2] = hb ? w1[2] : e0; c.w[3] = hb ? w1[3] : e1;
      pf[2] = c.v;
    }
    {
      const unsigned int e0 = exch32(w1[4]), e1 = exch32(w1[5]);
      const unsigned int e2 = exch32(w1[6]), e3 = exch32(w1[7]);
      Cv c;
      c.w[0] = hb ? e2 : w1[4]; c.w[1] = hb ? e3 : w1[5];
      c.w[2] = hb ? w1[6] : e0; c.w[3] = hb ? w1[7] : e1;
      pf[3] = c.v;
    }

    // O^T += V^T · P^T : A = V^T rows d = dh*32 + l31, keys 16t + hb*8 + j
    __builtin_amdgcn_s_setprio(1);
    {
      const unsigned short* vrow = vcur + l31 * 64;
#pragma unroll
      for (int t = 0; t < 4; ++t) {
        bf16x8_t vf = *(const bf16x8_t*)&vrow[((2 * t + hb) ^ swr0) << 3];
        oAcc[0] = __builtin_amdgcn_mfma_f32_32x32x16_bf16(vf, pf[t], oAcc[0], 0, 0, 0);
      }
    }
    {
      const unsigned short* vrow = vcur + (32 + l31) * 64;
#pragma unroll
      for (int t = 0; t < 4; ++t) {
        bf16x8_t vf = *(const bf16x8_t*)&vrow[((2 * t + hb) ^ swr1) << 3];
        oAcc[1] = __builtin_amdgcn_mfma_f32_32x32x16_bf16(vf, pf[t], oAcc[1], 0, 0, 0);
      }
    }
    __builtin_amdgcn_s_setprio(0);

    // single barrier per iter: drains this iter's prefetch (vmcnt) AND all waves' LDS reads
    __syncthreads();
    cur ^= 1;
  }
#undef STAGE

  // epilogue: lane owns q = q0+wv*32+l31; d = 32*dh + 8*a + 4*hb + c  (reg = 4a+c)
  const int bb = bh >> 4, hh = bh & 15;
  const float inv = 1.0f / lval;
  unsigned short* orow = Oattn + (size_t)(bb * SEQ + q0 + wv * 32 + l31) * D_MODEL
                       + hh * DK + hb * 4;
#pragma unroll
  for (int dh = 0; dh < 2; ++dh)
#pragma unroll
    for (int a = 0; a < 4; ++a) {
      const float v0 = oAcc[dh][4 * a]     * inv;
      const float v1 = oAcc[dh][4 * a + 1] * inv;
      const float v2 = oAcc[dh][4 * a + 2] * inv;
      const float v3 = oAcc[dh][4 * a + 3] * inv;
      *(uint2*)(orow + dh * 32 + a * 8) = make_uint2(pack2(v0, v1), pack2(v2, v3));
    }
}

extern "C" void kernel_launch(void* const* d_in, const int* in_sizes, int n_in,
                              void* d_out, int out_size, void* d_ws, size_t ws_size,
                              hipStream_t stream) {
  const float* query = (const float*)d_in[0];
  const float* key   = (const float*)d_in[1];
  const float* value = (const float*)d_in[2];
  const float* Wq    = (const float*)d_in[3];
  const float* bq    = (const float*)d_in[4];
  const float* Wk    = (const float*)d_in[5];
  const float* bk    = (const float*)d_in[6];
  const float* Wv    = (const float*)d_in[7];
  const float* bv    = (const float*)d_in[8];
  const float* Wo    = (const float*)d_in[9];
  const float* bo    = (const float*)d_in[10];

  const size_t E  = (size_t)BATCH * SEQ * D_MODEL;   // 8,388,608
  const size_t WE = (size_t)D_MODEL * D_MODEL;       // 1,048,576
  unsigned short* ws  = (unsigned short*)d_ws;
  unsigned short* Qws = ws;                          // [B,H,S,dk], pre-scaled log2e/8
  unsigned short* Kws = ws + E;
  unsigned short* Vws = ws + 2 * E;                  // [B,H,dk,S] transposed
  unsigned short* qb  = ws + 3 * E;
  unsigned short* kb  = ws + 4 * E;
  unsigned short* vb  = ws + 5 * E;
  unsigned short* wqb = ws + 6 * E;
  unsigned short* wkb = wqb + WE;
  unsigned short* wvb = wqb + 2 * WE;
  unsigned short* wob = wqb + 3 * WE;
  unsigned short* Aws = qb;                          // alias: qb dead after QKV GEMM

  cvt7_kernel<<<dim3(12288 + 2048), 256, 0, stream>>>(
      query, key, value, Wq, Wk, Wv, Wo, qb, kb, vb, wqb, wkb, wvb, wob);

  qkv_kernel<<<dim3(512, 1, 3), 256, 0, stream>>>(
      qb, kb, vb, wqb, wkb, wvb, bq, bk, bv, Qws, Kws, Vws);
  attn_kernel<<<dim3(BATCH * NHEADS, SEQ / 256), 512, 0, stream>>>(Qws, Kws, Vws, Aws);
  outproj_kernel<<<dim3(512), 256, 0, stream>>>(
      Aws, wob, bo, (float*)d_out);
}

// Round 12
// 352.419 us; speedup vs baseline: 1.0372x; 1.0070x over previous
//
#include <hip/hip_runtime.h>
#include <hip/hip_bf16.h>
#include <cstdint>
#include <cstddef>

// MultiHeadAttention B=4, S=2048, D=1024, H=16, dk=64. fp32 in/out, bf16 MFMA internals.
// cvt fp32->bf16 (fused launch) -> fused QKV gemm (BK=64 2-barrier core: half the
// barrier-drain stalls, 2x MFMA per phase; SWAPPED Q/K epilogues) -> flash attn
// (R7 512-thr structure, frozen at 113.5us) -> out proj (SWAPPED float4 epilogue).

#define BATCH   4
#define SEQ     2048
#define D_MODEL 1024
#define NHEADS  16
#define DK      64

typedef __attribute__((ext_vector_type(8)))  __bf16 bf16x8_t;
typedef __attribute__((ext_vector_type(4)))  float  f32x4;
typedef __attribute__((ext_vector_type(16))) float  f32x16;

// HW packed fp32->bf16 (v_cvt_pk_bf16_f32 on gfx950)
__device__ inline unsigned int pack2(float lo, float hi) {
  __hip_bfloat162 h = __float22bfloat162_rn(make_float2(lo, hi));
  union { __hip_bfloat162 h; unsigned int u; } c; c.h = h; return c.u;
}
__device__ inline unsigned short f2bf(float f) { return (unsigned short)pack2(f, f); }

#if __has_builtin(__builtin_amdgcn_exp2f)
__device__ inline float fexp2(float x) { return __builtin_amdgcn_exp2f(x); }
#else
__device__ inline float fexp2(float x) { return __expf(x * 0.6931471805599453f); }
#endif

__device__ inline unsigned int exch32(unsigned int x) {  // partner lane^32 (verified prim)
  return (unsigned int)__shfl_xor((int)x, 32);
}

__device__ inline void cvt8(const float* __restrict__ s, unsigned short* __restrict__ d) {
  const float4 a = *(const float4*)s;
  const float4 b = *(const float4*)(s + 4);
  uint4 r;
  r.x = pack2(a.x, a.y); r.y = pack2(a.z, a.w);
  r.z = pack2(b.x, b.y); r.w = pack2(b.z, b.w);
  *(uint4*)d = r;
}

// async global->LDS, 16B/lane; LDS dest = wave-uniform base + lane*16B
typedef __attribute__((address_space(3))) unsigned int lds_u32_t;
typedef const __attribute__((address_space(1))) unsigned int glb_u32_t;
__device__ inline void gld16(const unsigned short* g, unsigned short* l) {
  __builtin_amdgcn_global_load_lds((glb_u32_t*)(uintptr_t)g,
                                   (lds_u32_t*)(unsigned int)(uintptr_t)l, 16, 0, 0);
}

// ---------------- fused fp32 -> bf16 conversion (3 activations + 4 weights, one launch) ----------------
__global__ __launch_bounds__(256) void cvt7_kernel(
    const float* __restrict__ a, const float* __restrict__ b, const float* __restrict__ c,
    const float* __restrict__ w0, const float* __restrict__ w1,
    const float* __restrict__ w2, const float* __restrict__ w3,
    unsigned short* __restrict__ oa, unsigned short* __restrict__ ob, unsigned short* __restrict__ oc,
    unsigned short* __restrict__ ow0, unsigned short* __restrict__ ow1,
    unsigned short* __restrict__ ow2, unsigned short* __restrict__ ow3)
{
  const int bx = blockIdx.x;
  const float* s;
  unsigned short* d;
  size_t local;
  if (bx < 12288) {                      // 3 tensors x 4096 blocks (E elems each)
    const int t = bx >> 12;
    local = (size_t)(bx & 4095);
    s = (t == 0) ? a : (t == 1) ? b : c;
    d = (t == 0) ? oa : (t == 1) ? ob : oc;
  } else {                               // 4 weights x 512 blocks (WE elems each)
    const int t = (bx - 12288) >> 9;
    local = (size_t)((bx - 12288) & 511);
    s = (t == 0) ? w0 : (t == 1) ? w1 : (t == 2) ? w2 : w3;
    d = (t == 0) ? ow0 : (t == 1) ? ow1 : (t == 2) ? ow2 : ow3;
  }
  const size_t i = (local * 256 + threadIdx.x) * 8;
  cvt8(s + i, d + i);
}

// ---------------- shared GEMM core: BK=64, single-buffer 2-barrier ----------------
// 16 K-phases (vs 32 at BK=32): half the barrier-drain stalls, 32 MFMA per phase.
// LDS [128][64] shorts per operand (16 KiB each, 32 KiB total), unpadded.
// Staging: 256 thr = 32 rows x 8 chunks per gld16; 4 issues per operand cover 128 rows;
// all issues share row&7 = srow8&7 -> single source-side swizzle sch = chunk ^ (srow8&7).
// Bank balance: row stride 128 B -> bank-group = phys chunk; chunk^(row&7) spreads each
// logical chunk over 8 phys -> 8 lanes per 4-bank group per b128 read (balanced).
// SWAP=false: D[m=quad*4+reg, n=l15]  (C/D: col=lane&15, row=quad*4+reg [m89])
// SWAP=true : mfma(W,A) -> D[m=l15, n=quad*4+reg]
template <bool SWAP>
__device__ inline void gemm_core(const unsigned short* __restrict__ A,
                                 const unsigned short* __restrict__ W,
                                 unsigned short* a_lds, unsigned short* b_lds,
                                 int m0, int n0, f32x4 (&acc)[4][4])
{
  const int tid  = threadIdx.x;
  const int lane = tid & 63;
  const int wv   = tid >> 6;
  const int l15  = lane & 15;
  const int quad = lane >> 4;
  const int wm = (wv & 1) * 64;
  const int wn = (wv >> 1) * 64;

  const int srow8 = tid >> 3;            // 0..31
  const int sch   = (tid & 7) ^ (srow8 & 7);
  const unsigned short* Ap = A + (size_t)(m0 + srow8) * D_MODEL + sch * 8;
  const unsigned short* Wp = W + (size_t)(n0 + srow8) * D_MODEL + sch * 8;
  const int dstb = wv * 512;             // shorts; issue g adds g*2048

  const int swl = l15 & 7;               // row&7 for all fragment rows

  for (int k0 = 0; k0 < D_MODEL; k0 += 64) {
    __syncthreads();
#pragma unroll
    for (int g = 0; g < 4; ++g) {
      gld16(Ap + (size_t)(32 * g) * D_MODEL + k0, a_lds + g * 2048 + dstb);
      gld16(Wp + (size_t)(32 * g) * D_MODEL + k0, b_lds + g * 2048 + dstb);
    }
    __syncthreads();

#pragma unroll
    for (int kk = 0; kk < 2; ++kk) {
      bf16x8_t af[4], bfr[4];
#pragma unroll
      for (int i = 0; i < 4; ++i)
        af[i] = *(const bf16x8_t*)&a_lds[(wm + i * 16 + l15) * 64 + (((kk * 4 + quad) ^ swl) << 3)];
#pragma unroll
      for (int j = 0; j < 4; ++j)
        bfr[j] = *(const bf16x8_t*)&b_lds[(wn + j * 16 + l15) * 64 + (((kk * 4 + quad) ^ swl) << 3)];

#pragma unroll
      for (int i = 0; i < 4; ++i)
#pragma unroll
        for (int j = 0; j < 4; ++j) {
          if constexpr (SWAP)
            acc[i][j] = __builtin_amdgcn_mfma_f32_16x16x32_bf16(bfr[j], af[i], acc[i][j], 0, 0, 0);
          else
            acc[i][j] = __builtin_amdgcn_mfma_f32_16x16x32_bf16(af[i], bfr[j], acc[i][j], 0, 0, 0);
        }
    }
  }
}

// ---------------- fused QKV projection ----------------
// grid (M/128, N/128, 3). z=0: Q (scaled log2e/8, SWAPPED -> uint2 scatter [B,H,S,dk]);
// z=1: K (SWAPPED -> uint2); z=2: V TRANSPOSED [B,H,dk,S] (non-swapped -> uint2).
__global__ __launch_bounds__(256) void qkv_kernel(
    const unsigned short* __restrict__ qb, const unsigned short* __restrict__ kb,
    const unsigned short* __restrict__ vb,
    const unsigned short* __restrict__ wq, const unsigned short* __restrict__ wk,
    const unsigned short* __restrict__ wvp,
    const float* __restrict__ bq, const float* __restrict__ bk, const float* __restrict__ bv,
    unsigned short* __restrict__ Qws, unsigned short* __restrict__ Kws,
    unsigned short* __restrict__ Vws)
{
  __shared__ unsigned short a_lds[128 * 64];
  __shared__ unsigned short b_lds[128 * 64];

  const int z = blockIdx.z;
  const unsigned short* A = (z == 0) ? qb : (z == 1) ? kb : vb;
  const unsigned short* W = (z == 0) ? wq : (z == 1) ? wk : wvp;
  const float* bias       = (z == 0) ? bq : (z == 1) ? bk : bv;
  unsigned short* C       = (z == 0) ? Qws : (z == 1) ? Kws : Vws;
  const int m0 = blockIdx.x * 128;
  const int n0 = blockIdx.y * 128;

  f32x4 acc[4][4];
#pragma unroll
  for (int i = 0; i < 4; ++i)
#pragma unroll
    for (int j = 0; j < 4; ++j)
      acc[i][j] = (f32x4){0.f, 0.f, 0.f, 0.f};

  const int tid  = threadIdx.x;
  const int lane = tid & 63;
  const int wv   = tid >> 6;
  const int l15  = lane & 15;
  const int quad = lane >> 4;
  const int wm = (wv & 1) * 64;
  const int wn = (wv >> 1) * 64;

  if (z == 2) {
    gemm_core<false>(A, W, a_lds, b_lds, m0, n0, acc);
    // D[m=quad*4+reg, n=l15]; V^T: off = ((bb*H+hh)*DK+dd)*SEQ + ss; 4 consecutive ss -> uint2
    for (int j = 0; j < 4; ++j) {
      const int n = n0 + wn + j * 16 + l15;
      const int hh = n >> 6, dd = n & 63;
      const float bvl = bias[n];
      for (int i = 0; i < 4; ++i) {
        const int mbase = m0 + wm + i * 16 + quad * 4;
        const int bb = mbase >> 11, ss = mbase & 2047;
        uint2 w2 = make_uint2(pack2(acc[i][j][0] + bvl, acc[i][j][1] + bvl),
                              pack2(acc[i][j][2] + bvl, acc[i][j][3] + bvl));
        *(uint2*)(C + (((size_t)bb * NHEADS + hh) * DK + dd) * SEQ + ss) = w2;
      }
    }
  } else {
    gemm_core<true>(A, W, a_lds, b_lds, m0, n0, acc);
    // SWAPPED: D[m=l15, n=quad*4+reg] -> 4 consecutive dd per lane (same head: quad*4+3<64)
    const float oscale = (z == 0) ? 0.18033688011112042f : 1.0f;  // log2(e)/8 for Q
    for (int j = 0; j < 4; ++j) {
      const int nb = n0 + wn + j * 16 + quad * 4;
      const int hh = nb >> 6, dd = nb & 63;
      const float4 b4 = *(const float4*)(bias + nb);
      for (int i = 0; i < 4; ++i) {
        const int m = m0 + wm + i * 16 + l15;
        const int bb = m >> 11, ss = m & 2047;
        uint2 w2 = make_uint2(pack2((acc[i][j][0] + b4.x) * oscale, (acc[i][j][1] + b4.y) * oscale),
                              pack2((acc[i][j][2] + b4.z) * oscale, (acc[i][j][3] + b4.w) * oscale));
        *(uint2*)(C + (((size_t)bb * NHEADS + hh) * SEQ + ss) * DK + dd) = w2;
      }
    }
  }
}

// ---------------- output projection (bf16 A, fp32 out, SWAPPED -> float4 epilogue) ----------------
__global__ __launch_bounds__(256) void outproj_kernel(
    const unsigned short* __restrict__ A, const unsigned short* __restrict__ W,
    const float* __restrict__ bias, float* __restrict__ C)
{
  __shared__ unsigned short a_lds[128 * 64];
  __shared__ unsigned short b_lds[128 * 64];
  const int m0 = blockIdx.x * 128;
  const int n0 = blockIdx.y * 128;

  f32x4 acc[4][4];
#pragma unroll
  for (int i = 0; i < 4; ++i)
#pragma unroll
    for (int j = 0; j < 4; ++j)
      acc[i][j] = (f32x4){0.f, 0.f, 0.f, 0.f};

  gemm_core<true>(A, W, a_lds, b_lds, m0, n0, acc);

  const int tid  = threadIdx.x;
  const int lane = tid & 63;
  const int wv   = tid >> 6;
  const int l15  = lane & 15;
  const int quad = lane >> 4;
  const int wm = (wv & 1) * 64;
  const int wn = (wv >> 1) * 64;
  // SWAPPED: D[m=l15, n=quad*4+reg] -> float4 store (nb 4-aligned -> 16B aligned)
  for (int j = 0; j < 4; ++j) {
    const int nb = n0 + wn + j * 16 + quad * 4;
    const float4 b4 = *(const float4*)(bias + nb);
    for (int i = 0; i < 4; ++i) {
      const int m = m0 + wm + i * 16 + l15;
      float4 o4 = make_float4(acc[i][j][0] + b4.x, acc[i][j][1] + b4.y,
                              acc[i][j][2] + b4.z, acc[i][j][3] + b4.w);
      *(float4*)(C + (size_t)m * D_MODEL + nb) = o4;
    }
  }
}

// ---------------- Flash attention, swapped 32x32x16 form (R7, frozen at 113.5us) ----------------
// 512 thr (8 waves), wave wv owns 32 q-rows (q0 + wv*32 + l31); grid (B*H, S/256).
// S^T[64k x 32q] = K·Q^T via 2 key-slices x 4 dk-slices of mfma_32x32x16.
//   C/D: col = lane&31 = q, row = (reg&3)+8*(reg>>2)+4*(lane>>5)  [m74/m101]
// Cross-half combines + P^T B-fragment build via __shfl_xor(.,32).
// K/V^T DMA-staged double-buffered, source-side XOR swizzle chunk^(row&7)^(row>>3).
__global__ __launch_bounds__(512, 4) void attn_kernel(
    const unsigned short* __restrict__ Q,    // [B,H,S,dk]
    const unsigned short* __restrict__ K,    // [B,H,S,dk]
    const unsigned short* __restrict__ Vt,   // [B,H,dk,S]  (pre-transposed)
    unsigned short* __restrict__ Oattn)      // [B,S,D]
{
  __shared__ unsigned short k_sw[2 * 64 * 64];
  __shared__ unsigned short vt_sw[2 * 64 * 64];

  const int tid  = threadIdx.x;
  const int lane = tid & 63;
  const int wv   = tid >> 6;              // 0..7
  const int l31  = lane & 31;
  const int hb   = lane >> 5;             // half index
  const int bh   = blockIdx.x;            // bh-major: XCD = bh%8 -> K/V L2 locality
  const int q0   = blockIdx.y * 256;
  const size_t hoff = (size_t)bh * SEQ * DK;
  const unsigned short* Qh  = Q  + hoff;
  const unsigned short* Kh  = K  + hoff;
  const unsigned short* Vth = Vt + hoff;

  // Q fragments: q = q0 + wv*32 + l31, dk = kk*16 + hb*8 + j
  bf16x8_t qf[4];
  {
    const unsigned short* qr = Qh + (size_t)(q0 + wv * 32 + l31) * DK;
#pragma unroll
    for (int kk = 0; kk < 4; ++kk)
      qf[kk] = *(const bf16x8_t*)(qr + kk * 16 + hb * 8);
  }

  f32x16 oAcc[2];
#pragma unroll
  for (int dh = 0; dh < 2; ++dh)
#pragma unroll
    for (int i = 0; i < 16; ++i) oAcc[dh][i] = 0.f;
  float mval = -1e30f, lval = 0.f;

  // DMA staging: wave wv covers tile rows [wv*8, wv*8+8) of K and of V^T (1 gld16 each).
  const int sr  = lane >> 3;              // 0..7 (row within the wave's 8-row slab)
  const int pc  = lane & 7;               // phys chunk
  const int row = wv * 8 + sr;
  const int sem = pc ^ sr ^ wv;           // (row&7)=sr, (row>>3)=wv
  const unsigned short* KsA = Kh  + (size_t)row * DK  + sem * 8;   // + key0*DK per iter
  const unsigned short* VsA = Vth + (size_t)row * SEQ + sem * 8;   // + key0 per iter
  unsigned short* kd = k_sw  + wv * 512;
  unsigned short* vd = vt_sw + wv * 512;

#define STAGE(buf, key0) do {                                        \
    gld16(KsA + (size_t)(key0) * DK, kd + (buf) * 4096);             \
    gld16(VsA + (key0),              vd + (buf) * 4096);             \
  } while (0)

  // prologue: stage tile 0 into buffer 0
  STAGE(0, 0);
  __syncthreads();                         // drains vmcnt(0): tile 0 resident

  const int swr0 = (l31 & 7) ^ (l31 >> 3);         // swizzle for rows l31      (slice 0)
  const int swr1 = (l31 & 7) ^ ((l31 >> 3) ^ 4);   // swizzle for rows 32+l31   (slice 1)

  int cur = 0;
  for (int kb = 0; kb < SEQ / 64; ++kb) {
    // issue next tile's loads FIRST so they overlap this tile's compute
    if (kb + 1 < SEQ / 64) STAGE(cur ^ 1, (kb + 1) * 64);

    const unsigned short* kcur = k_sw  + cur * 4096;
    const unsigned short* vcur = vt_sw + cur * 4096;

    // S^T = K·Q^T : s0 = keys 0..31 rows, s1 = keys 32..63 rows (per C/D row map)
    f32x16 s0, s1;
#pragma unroll
    for (int i = 0; i < 16; ++i) { s0[i] = 0.f; s1[i] = 0.f; }
    __builtin_amdgcn_s_setprio(1);
    {
      const unsigned short* krow = kcur + l31 * 64;
#pragma unroll
      for (int kk = 0; kk < 4; ++kk) {
        bf16x8_t kf = *(const bf16x8_t*)&krow[((2 * kk + hb) ^ swr0) << 3];
        s0 = __builtin_amdgcn_mfma_f32_32x32x16_bf16(kf, qf[kk], s0, 0, 0, 0);
      }
    }
    {
      const unsigned short* krow = kcur + (32 + l31) * 64;
#pragma unroll
      for (int kk = 0; kk < 4; ++kk) {
        bf16x8_t kf = *(const bf16x8_t*)&krow[((2 * kk + hb) ^ swr1) << 3];
        s1 = __builtin_amdgcn_mfma_f32_32x32x16_bf16(kf, qf[kk], s1, 0, 0, 0);
      }
    }
    __builtin_amdgcn_s_setprio(0);

    // row-max over own 32 scores + cross-half combine (verified shfl_xor)
    float mx = s0[0];
#pragma unroll
    for (int i = 1; i < 16; ++i) mx = fmaxf(mx, s0[i]);
#pragma unroll
    for (int i = 0; i < 16; ++i) mx = fmaxf(mx, s1[i]);
    mx = fmaxf(mx, __shfl_xor(mx, 32));
    // defer-max (T13, THR=8 in base-2 units => P <= 2^8)
    if (__any(mx > mval + 8.0f)) {
      const float mnew  = fmaxf(mval, mx);
      const float alpha = fexp2(mval - mnew);
      mval = mnew;
      lval *= alpha;
#pragma unroll
      for (int dh = 0; dh < 2; ++dh)
#pragma unroll
        for (int i = 0; i < 16; ++i) oAcc[dh][i] *= alpha;
    }
    // p = exp2(s - m), pack to bf16 words; w[m] = pack(regs 2m, 2m+1)
    float rs = 0.f;
    unsigned int w0[8], w1[8];
#pragma unroll
    for (int m = 0; m < 8; ++m) {
      const float p0 = fexp2(s0[2 * m] - mval);
      const float p1 = fexp2(s0[2 * m + 1] - mval);
      rs += p0 + p1;
      w0[m] = pack2(p0, p1);
    }
#pragma unroll
    for (int m = 0; m < 8; ++m) {
      const float p0 = fexp2(s1[2 * m] - mval);
      const float p1 = fexp2(s1[2 * m + 1] - mval);
      rs += p0 + p1;
      w1[m] = pack2(p0, p1);
    }
    rs += __shfl_xor(rs, 32);
    lval += rs;

    // P^T -> PV B-fragments via verified cross-half exchange
    union Cv { unsigned int w[4]; bf16x8_t v; };
    bf16x8_t pf[4];
    {
      const unsigned int e0 = exch32(w0[0]), e1 = exch32(w0[1]);
      const unsigned int e2 = exch32(w0[2]), e3 = exch32(w0[3]);
      Cv c;
      c.w[0] = hb ? e2 : w0[0]; c.w[1] = hb ? e3 : w0[1];
      c.w[2] = hb ? w0[2] : e0; c.w[3] = hb ? w0[3] : e1;
      pf[0] = c.v;
    }
    {
      const unsigned int e0 = exch32(w0[4]), e1 = exch32(w0[5]);
      const unsigned int e2 = exch32(w0[6]), e3 = exch32(w0[7]);
      Cv c;
      c.w[0] = hb ? e2 : w0[4]; c.w[1] = hb ? e3 : w0[5];
      c.w[2] = hb ? w0[6] : e0; c.w[3] = hb ? w0[7] : e1;
      pf[1] = c.v;
    }
    {
      const unsigned int e0 = exch32(w1[0]), e1 = exch32(w1[1]);
      const unsigned int e2 = exch32(w1[2]), e3 = exch32(w1[3]);
      Cv c;
      c.w[0] = hb ? e2 : w1[0]; c.w[1] = hb ? e3 : w1[1];
      c.w[2] = hb ? w1[2] : e0; c.w[3] = hb ? w1[3] : e1;
      pf[2] = c.v;
    }
    {
      const unsigned int e0 = exch32(w1[4]), e1 = exch32(w1[5]);
      const unsigned int e2 = exch32(w1[6]), e3 = exch32(w1[7]);
      Cv c;
      c.w[0] = hb ? e2 : w1[4]; c.w[1] = hb ? e3 : w1[5];
      c.w[2] = hb ? w1[6] : e0; c.w[3] = hb ? w1[7] : e1;
      pf[3] = c.v;
    }

    // O^T += V^T · P^T : A = V^T rows d = dh*32 + l31, keys 16t + hb*8 + j
    __builtin_amdgcn_s_setprio(1);
    {
      const unsigned short* vrow = vcur + l31 * 64;
#pragma unroll
      for (int t = 0; t < 4; ++t) {
        bf16x8_t vf = *(const bf16x8_t*)&vrow[((2 * t + hb) ^ swr0) << 3];
        oAcc[0] = __builtin_amdgcn_mfma_f32_32x32x16_bf16(vf, pf[t], oAcc[0], 0, 0, 0);
      }
    }
    {
      const unsigned short* vrow = vcur + (32 + l31) * 64;
#pragma unroll
      for (int t = 0; t < 4; ++t) {
        bf16x8_t vf = *(const bf16x8_t*)&vrow[((2 * t + hb) ^ swr1) << 3];
        oAcc[1] = __builtin_amdgcn_mfma_f32_32x32x16_bf16(vf, pf[t], oAcc[1], 0, 0, 0);
      }
    }
    __builtin_amdgcn_s_setprio(0);

    // single barrier per iter: drains this iter's prefetch (vmcnt) AND all waves' LDS reads
    __syncthreads();
    cur ^= 1;
  }
#undef STAGE

  // epilogue: lane owns q = q0+wv*32+l31; d = 32*dh + 8*a + 4*hb + c  (reg = 4a+c)
  const int bb = bh >> 4, hh = bh & 15;
  const float inv = 1.0f / lval;
  unsigned short* orow = Oattn + (size_t)(bb * SEQ + q0 + wv * 32 + l31) * D_MODEL
                       + hh * DK + hb * 4;
#pragma unroll
  for (int dh = 0; dh < 2; ++dh)
#pragma unroll
    for (int a = 0; a < 4; ++a) {
      const float v0 = oAcc[dh][4 * a]     * inv;
      const float v1 = oAcc[dh][4 * a + 1] * inv;
      const float v2 = oAcc[dh][4 * a + 2] * inv;
      const float v3 = oAcc[dh][4 * a + 3] * inv;
      *(uint2*)(orow + dh * 32 + a * 8) = make_uint2(pack2(v0, v1), pack2(v2, v3));
    }
}

extern "C" void kernel_launch(void* const* d_in, const int* in_sizes, int n_in,
                              void* d_out, int out_size, void* d_ws, size_t ws_size,
                              hipStream_t stream) {
  const float* query = (const float*)d_in[0];
  const float* key   = (const float*)d_in[1];
  const float* value = (const float*)d_in[2];
  const float* Wq    = (const float*)d_in[3];
  const float* bq    = (const float*)d_in[4];
  const float* Wk    = (const float*)d_in[5];
  const float* bk    = (const float*)d_in[6];
  const float* Wv    = (const float*)d_in[7];
  const float* bv    = (const float*)d_in[8];
  const float* Wo    = (const float*)d_in[9];
  const float* bo    = (const float*)d_in[10];

  const size_t E  = (size_t)BATCH * SEQ * D_MODEL;   // 8,388,608
  const size_t WE = (size_t)D_MODEL * D_MODEL;       // 1,048,576
  unsigned short* ws  = (unsigned short*)d_ws;
  unsigned short* Qws = ws;                          // [B,H,S,dk], pre-scaled log2e/8
  unsigned short* Kws = ws + E;
  unsigned short* Vws = ws + 2 * E;                  // [B,H,dk,S] transposed
  unsigned short* qb  = ws + 3 * E;
  unsigned short* kb  = ws + 4 * E;
  unsigned short* vb  = ws + 5 * E;
  unsigned short* wqb = ws + 6 * E;
  unsigned short* wkb = wqb + WE;
  unsigned short* wvb = wqb + 2 * WE;
  unsigned short* wob = wqb + 3 * WE;
  unsigned short* Aws = qb;                          // alias: qb dead after QKV GEMM

  cvt7_kernel<<<dim3(12288 + 2048), 256, 0, stream>>>(
      query, key, value, Wq, Wk, Wv, Wo, qb, kb, vb, wqb, wkb, wvb, wob);

  qkv_kernel<<<dim3(BATCH * SEQ / 128, D_MODEL / 128, 3), 256, 0, stream>>>(
      qb, kb, vb, wqb, wkb, wvb, bq, bk, bv, Qws, Kws, Vws);
  attn_kernel<<<dim3(BATCH * NHEADS, SEQ / 256), 512, 0, stream>>>(Qws, Kws, Vws, Aws);
  outproj_kernel<<<dim3(BATCH * SEQ / 128, D_MODEL / 128), 256, 0, stream>>>(
      Aws, wob, bo, (float*)d_out);
}